// Round 6
// baseline (138.135 us; speedup 1.0000x reference)
//
#include <hip/hip_runtime.h>
#include <hip/hip_bf16.h>
#include <math.h>

#define N_NEUR 2048
#define EMB 1024
#define S_TOT 8192
#define NW 12

typedef __attribute__((ext_vector_type(8))) short bf16x8;
typedef __attribute__((ext_vector_type(4))) float f32x4;

__device__ inline short f2bf(float f) {
    union { float f; unsigned u; } v; v.f = f;
    unsigned r = v.u + 0x7FFFu + ((v.u >> 16) & 1u);   // RNE
    return (short)(r >> 16);
}

// Cast x-tail (rows 6144..8191) and n_weights to bf16; also zero seg + ctr.
__global__ __launch_bounds__(256) void precast(const float* __restrict__ xt,
                                               const float* __restrict__ nw,
                                               short* __restrict__ A,
                                               short* __restrict__ W,
                                               float* __restrict__ seg,
                                               int* __restrict__ ctr) {
    const int HALF = (N_NEUR * EMB) / 4;   // 524288 float4 groups per matrix
    int g = blockIdx.x * 256 + threadIdx.x;
    if (g < (NW * N_NEUR) / 4) ((float4*)seg)[g] = make_float4(0.f, 0.f, 0.f, 0.f);
    if (g == (NW * N_NEUR) / 4) *ctr = 0;
    int gg = g;
    const float4* src; short* dst;
    if (gg < HALF) { src = (const float4*)xt; dst = A; }
    else           { gg -= HALF; src = (const float4*)nw; dst = W; }
    float4 v = src[gg];
    short4 o;
    o.x = f2bf(v.x); o.y = f2bf(v.y); o.z = f2bf(v.z); o.w = f2bf(v.w);
    *(short4*)(dst + (size_t)gg * 4) = o;
}

// Fused GEMM + tanh + segment-sum + (last block) window-prefix + out-init.
// 64x64 tile, BK=64, 4 waves (2x2 of 32x32) -> 1024 blocks = 4/CU (proven R4
// config; 128x128 at 1 block/CU serialized on the barrier vmcnt drain).
// global_load_lds(16B) staging, double-buffered LDS, one barrier per K-step.
// XOR slot-swizzle (slot ^= row&7, 16B chunks) on BOTH global source address
// and ds_read address (rule 21: both-sides-or-neither).
#define GLDS(g, l) __builtin_amdgcn_global_load_lds(                          \
    (const __attribute__((address_space(1))) void*)(g),                       \
    (__attribute__((address_space(3))) void*)(l), 16, 0, 0)

__global__ __launch_bounds__(256) void gemm_seg(const short* __restrict__ A,
                                                const short* __restrict__ W,
                                                const float* __restrict__ bias,
                                                const float* __restrict__ cb,
                                                float* __restrict__ seg,
                                                float* __restrict__ wout,
                                                float* __restrict__ out,
                                                int* __restrict__ ctr) {
    __shared__ short As[2][64 * 64];
    __shared__ short Bs[2][64 * 64];
    const int t = threadIdx.x;
    const int bm = blockIdx.y, bn = blockIdx.x;
    const int lane = t & 63, wid = t >> 6;
    const int wr = wid >> 1, wc = wid & 1;
    const int l15 = lane & 15, lhi = lane >> 4;
    // Staging: wave wid stages rows [wid*16, wid*16+16) in two 8-row 1KB
    // issues; source slot pre-swizzled: pslot = (lane&7) ^ (row&7).
    const int srow = lane >> 3;            // 0..7 within issue
    const int pslot = (lane & 7) ^ srow;
    const short* gA0 = A + (size_t)(bm * 64 + wid * 16 + 0 + srow) * EMB + pslot * 8;
    const short* gA1 = A + (size_t)(bm * 64 + wid * 16 + 8 + srow) * EMB + pslot * 8;
    const short* gB0 = W + (size_t)(bn * 64 + wid * 16 + 0 + srow) * EMB + pslot * 8;
    const short* gB1 = W + (size_t)(bn * 64 + wid * 16 + 8 + srow) * EMB + pslot * 8;
    short* lA0[2] = { &As[0][(wid * 16 + 0) * 64], &As[1][(wid * 16 + 0) * 64] };
    short* lA1[2] = { &As[0][(wid * 16 + 8) * 64], &As[1][(wid * 16 + 8) * 64] };
    short* lB0[2] = { &Bs[0][(wid * 16 + 0) * 64], &Bs[1][(wid * 16 + 0) * 64] };
    short* lB1[2] = { &Bs[0][(wid * 16 + 8) * 64], &Bs[1][(wid * 16 + 8) * 64] };

    f32x4 acc[2][2] = {};

    GLDS(gA0, lA0[0]); GLDS(gA1, lA1[0]);
    GLDS(gB0, lB0[0]); GLDS(gB1, lB1[0]);
    __syncthreads();

    int cur = 0;
    for (int ks = 0; ks < 16; ++ks) {
        if (ks < 15) {
            int k0 = (ks + 1) * 64;
            GLDS(gA0 + k0, lA0[cur ^ 1]); GLDS(gA1 + k0, lA1[cur ^ 1]);
            GLDS(gB0 + k0, lB0[cur ^ 1]); GLDS(gB1 + k0, lB1[cur ^ 1]);
        }
        bf16x8 af[2][2], bb[2][2];
        #pragma unroll
        for (int kk = 0; kk < 2; ++kk) {
            #pragma unroll
            for (int m = 0; m < 2; ++m) {
                int row = wr * 32 + m * 16 + l15;
                int slot = (kk * 4 + lhi) ^ (row & 7);
                af[kk][m] = *(const bf16x8*)&As[cur][row * 64 + slot * 8];
            }
            #pragma unroll
            for (int n = 0; n < 2; ++n) {
                int row = wc * 32 + n * 16 + l15;
                int slot = (kk * 4 + lhi) ^ (row & 7);
                bb[kk][n] = *(const bf16x8*)&Bs[cur][row * 64 + slot * 8];
            }
        }
        __builtin_amdgcn_s_setprio(1);
        #pragma unroll
        for (int kk = 0; kk < 2; ++kk)
            #pragma unroll
            for (int m = 0; m < 2; ++m)
                #pragma unroll
                for (int n = 0; n < 2; ++n)
                    acc[m][n] = __builtin_amdgcn_mfma_f32_16x16x32_bf16(af[kk][m], bb[kk][n], acc[m][n], 0, 0, 0);
        __builtin_amdgcn_s_setprio(0);
        __syncthreads();
        cur ^= 1;
    }

    // Epilogue. C/D layout: col = lane&15, row(within frag) = lhi*4 + j.
    if (bm > 0) {
        int jseg = 38 - __clz(bm);   // floor(log2(bm*64)) + 1
        #pragma unroll
        for (int n = 0; n < 2; ++n) {
            int col = bn * 64 + wc * 32 + n * 16 + l15;
            float bc = bias[col];
            float s = 0.f;
            #pragma unroll
            for (int m = 0; m < 2; ++m)
                #pragma unroll
                for (int j = 0; j < 4; ++j)
                    s += tanhf(acc[m][n][j] + bc);
            s += __shfl_xor(s, 16);
            s += __shfl_xor(s, 32);
            if (lhi == 0) atomicAdd(&seg[jseg * N_NEUR + col], s);
        }
    } else {
        #pragma unroll
        for (int n = 0; n < 2; ++n) {
            int col = bn * 64 + wc * 32 + n * 16 + l15;
            float bc = bias[col];
            if (wr == 1) {                 // rows 32..63 -> seg 6
                float s = 0.f;
                #pragma unroll
                for (int m = 0; m < 2; ++m)
                    #pragma unroll
                    for (int j = 0; j < 4; ++j)
                        s += tanhf(acc[m][n][j] + bc);
                s += __shfl_xor(s, 16);
                s += __shfl_xor(s, 32);
                if (lhi == 0) atomicAdd(&seg[6 * N_NEUR + col], s);
            } else {
                float s = 0.f;             // rows 16..31 -> seg 5
                #pragma unroll
                for (int j = 0; j < 4; ++j)
                    s += tanhf(acc[1][n][j] + bc);
                s += __shfl_xor(s, 16);
                s += __shfl_xor(s, 32);
                if (lhi == 0) atomicAdd(&seg[5 * N_NEUR + col], s);
                #pragma unroll
                for (int j = 0; j < 4; ++j) {  // rows 0..15 per-row segments
                    int r = lhi * 4 + j;
                    int sj = (r == 0) ? 0 : (32 - __clz(r));
                    atomicAdd(&seg[sj * N_NEUR + col], tanhf(acc[0][n][j] + bc));
                }
            }
        }
    }

    // Last-block-done: compute wout prefix + initialize out (proven in R5).
    __shared__ int lastblk;
    __threadfence();
    if (t == 0) lastblk = (atomicAdd(ctr, 1) == 1023);
    __syncthreads();
    if (lastblk) {
        __threadfence();
        const volatile float* vseg = (const volatile float*)seg;
        for (int n = t; n < N_NEUR; n += 256) {
            float run = 0.f;
            #pragma unroll
            for (int w = 0; w < NW; ++w) {
                run += vseg[w * N_NEUR + n];
                wout[w * N_NEUR + n] = run * (1.0f / (float)(1 << w));
            }
            float bs = 0.f;
            #pragma unroll
            for (int w = 0; w < NW; ++w) bs += cb[w * N_NEUR + n];
            out[n] = 1.0166666666666666f * bs + 1.0f;
        }
    }
}

// out[m] += (61/60) * dot(combo_w[w][m][:], wout[w][:]) ; one wave per (w,m).
__global__ __launch_bounds__(256) void combo_dot(const float* __restrict__ cw,
                                                 const float* __restrict__ wout,
                                                 float* __restrict__ out) {
    int wid = threadIdx.x >> 6, lane = threadIdx.x & 63;
    int r = blockIdx.x * 4 + wid;             // 0..24575
    int w = r >> 11, m = r & 2047;
    const float4* row  = (const float4*)(cw + (size_t)(w * N_NEUR + m) * N_NEUR);
    const float4* wrow = (const float4*)(wout + w * N_NEUR);
    float s = 0.f;
    #pragma unroll
    for (int i = 0; i < 8; ++i) {
        float4 a = row[i * 64 + lane];
        float4 b = wrow[i * 64 + lane];
        s += a.x * b.x + a.y * b.y + a.z * b.z + a.w * b.w;
    }
    #pragma unroll
    for (int off = 32; off > 0; off >>= 1) s += __shfl_down(s, off);
    if (lane == 0) atomicAdd(&out[m], 1.0166666666666666f * s);
}

extern "C" void kernel_launch(void* const* d_in, const int* in_sizes, int n_in,
                              void* d_out, int out_size, void* d_ws, size_t ws_size,
                              hipStream_t stream) {
    const float* x  = (const float*)d_in[0];
    const float* nw = (const float*)d_in[1];
    const float* nb = (const float*)d_in[2];
    const float* cw = (const float*)d_in[3];
    const float* cb = (const float*)d_in[4];
    float* out = (float*)d_out;

    char* ws = (char*)d_ws;
    float* seg  = (float*)ws;                              // 12*2048 f32   (96 KB)
    float* wout = (float*)(ws + 98304);                    // 12*2048 f32   (96 KB)
    int*   ctr  = (int*)(ws + 196608);                     // 1 int
    short* Abf  = (short*)(ws + 204800);                   // 2048*1024 bf16 (4 MB)
    short* Wbf  = (short*)(ws + 204800 + 4194304);         // 2048*1024 bf16 (4 MB)

    precast<<<4096, 256, 0, stream>>>(x + (size_t)(S_TOT - 2048) * EMB, nw, Abf, Wbf, seg, ctr);

    dim3 g1(32, 32);
    gemm_seg<<<g1, 256, 0, stream>>>(Abf, Wbf, nb, cb, seg, wout, out, ctr);

    combo_dot<<<6144, 256, 0, stream>>>(cw, wout, out);
}

// Round 7
// 57.029 us; speedup vs baseline: 2.4222x; 2.4222x over previous
//
#include <hip/hip_runtime.h>
#include <hip/hip_bf16.h>
#include <math.h>

#define N_NEUR 2048
#define EMB 1024
#define S_TOT 8192
#define NW 12

typedef __attribute__((ext_vector_type(8))) short bf16x8;
typedef __attribute__((ext_vector_type(4))) float f32x4;

__device__ inline short f2bf(float f) {
    union { float f; unsigned u; } v; v.f = f;
    unsigned r = v.u + 0x7FFFu + ((v.u >> 16) & 1u);   // RNE
    return (short)(r >> 16);
}

// Cast x-tail (rows 6144..8191) and n_weights to bf16; also zero seg.
// (No fences needed: kernel boundary orders these writes for gemm_seg.)
__global__ __launch_bounds__(256) void precast(const float* __restrict__ xt,
                                               const float* __restrict__ nw,
                                               short* __restrict__ A,
                                               short* __restrict__ W,
                                               float* __restrict__ seg) {
    const int HALF = (N_NEUR * EMB) / 4;   // 524288 float4 groups per matrix
    int g = blockIdx.x * 256 + threadIdx.x;
    if (g < (NW * N_NEUR) / 4) ((float4*)seg)[g] = make_float4(0.f, 0.f, 0.f, 0.f);
    int gg = g;
    const float4* src; short* dst;
    if (gg < HALF) { src = (const float4*)xt; dst = A; }
    else           { gg -= HALF; src = (const float4*)nw; dst = W; }
    float4 v = src[gg];
    short4 o;
    o.x = f2bf(v.x); o.y = f2bf(v.y); o.z = f2bf(v.z); o.w = f2bf(v.w);
    *(short4*)(dst + (size_t)gg * 4) = o;
}

// Fused GEMM + tanh + segment-sum.  64x64 tile, BK=64, 4 waves (2x2 of 32x32),
// 1024 blocks = 4/CU.  global_load_lds(16B) staging, double-buffered LDS, one
// barrier per K-step.  XOR slot-swizzle (slot ^= row&7, 16B chunks) applied on
// BOTH the pre-swizzled global source address and the ds_read address.
// NOTE (R6 lesson): NO cross-block fusion here — per-block __threadfence()
// forces an L2 writeback per block on multi-XCD CDNA4 (+70 us observed).
#define GLDS(g, l) __builtin_amdgcn_global_load_lds(                          \
    (const __attribute__((address_space(1))) void*)(g),                       \
    (__attribute__((address_space(3))) void*)(l), 16, 0, 0)

__global__ __launch_bounds__(256) void gemm_seg(const short* __restrict__ A,
                                                const short* __restrict__ W,
                                                const float* __restrict__ bias,
                                                float* __restrict__ seg) {
    __shared__ short As[2][64 * 64];
    __shared__ short Bs[2][64 * 64];
    const int t = threadIdx.x;
    const int bm = blockIdx.y, bn = blockIdx.x;
    const int lane = t & 63, wid = t >> 6;
    const int wr = wid >> 1, wc = wid & 1;
    const int l15 = lane & 15, lhi = lane >> 4;
    const int srow = lane >> 3;            // 0..7 within 8-row issue
    const int pslot = (lane & 7) ^ srow;   // pre-swizzled source slot
    const short* gA0 = A + (size_t)(bm * 64 + wid * 16 + 0 + srow) * EMB + pslot * 8;
    const short* gA1 = A + (size_t)(bm * 64 + wid * 16 + 8 + srow) * EMB + pslot * 8;
    const short* gB0 = W + (size_t)(bn * 64 + wid * 16 + 0 + srow) * EMB + pslot * 8;
    const short* gB1 = W + (size_t)(bn * 64 + wid * 16 + 8 + srow) * EMB + pslot * 8;
    short* lA0[2] = { &As[0][(wid * 16 + 0) * 64], &As[1][(wid * 16 + 0) * 64] };
    short* lA1[2] = { &As[0][(wid * 16 + 8) * 64], &As[1][(wid * 16 + 8) * 64] };
    short* lB0[2] = { &Bs[0][(wid * 16 + 0) * 64], &Bs[1][(wid * 16 + 0) * 64] };
    short* lB1[2] = { &Bs[0][(wid * 16 + 8) * 64], &Bs[1][(wid * 16 + 8) * 64] };

    f32x4 acc[2][2] = {};

    GLDS(gA0, lA0[0]); GLDS(gA1, lA1[0]);
    GLDS(gB0, lB0[0]); GLDS(gB1, lB1[0]);
    __syncthreads();

    int cur = 0;
    for (int ks = 0; ks < 16; ++ks) {
        if (ks < 15) {
            int k0 = (ks + 1) * 64;
            GLDS(gA0 + k0, lA0[cur ^ 1]); GLDS(gA1 + k0, lA1[cur ^ 1]);
            GLDS(gB0 + k0, lB0[cur ^ 1]); GLDS(gB1 + k0, lB1[cur ^ 1]);
        }
        bf16x8 af[2][2], bb[2][2];
        #pragma unroll
        for (int kk = 0; kk < 2; ++kk) {
            #pragma unroll
            for (int m = 0; m < 2; ++m) {
                int row = wr * 32 + m * 16 + l15;
                int slot = (kk * 4 + lhi) ^ (row & 7);
                af[kk][m] = *(const bf16x8*)&As[cur][row * 64 + slot * 8];
            }
            #pragma unroll
            for (int n = 0; n < 2; ++n) {
                int row = wc * 32 + n * 16 + l15;
                int slot = (kk * 4 + lhi) ^ (row & 7);
                bb[kk][n] = *(const bf16x8*)&Bs[cur][row * 64 + slot * 8];
            }
        }
        __builtin_amdgcn_s_setprio(1);
        #pragma unroll
        for (int kk = 0; kk < 2; ++kk)
            #pragma unroll
            for (int m = 0; m < 2; ++m)
                #pragma unroll
                for (int n = 0; n < 2; ++n)
                    acc[m][n] = __builtin_amdgcn_mfma_f32_16x16x32_bf16(af[kk][m], bb[kk][n], acc[m][n], 0, 0, 0);
        __builtin_amdgcn_s_setprio(0);
        __syncthreads();
        cur ^= 1;
    }

    // Epilogue. C/D layout: col = lane&15, row(within frag) = lhi*4 + j.
    if (bm > 0) {
        int jseg = 38 - __clz(bm);   // floor(log2(bm*64)) + 1
        #pragma unroll
        for (int n = 0; n < 2; ++n) {
            int col = bn * 64 + wc * 32 + n * 16 + l15;
            float bc = bias[col];
            float s = 0.f;
            #pragma unroll
            for (int m = 0; m < 2; ++m)
                #pragma unroll
                for (int j = 0; j < 4; ++j)
                    s += tanhf(acc[m][n][j] + bc);
            s += __shfl_xor(s, 16);
            s += __shfl_xor(s, 32);
            if (lhi == 0) atomicAdd(&seg[jseg * N_NEUR + col], s);
        }
    } else {
        #pragma unroll
        for (int n = 0; n < 2; ++n) {
            int col = bn * 64 + wc * 32 + n * 16 + l15;
            float bc = bias[col];
            if (wr == 1) {                 // rows 32..63 -> seg 6
                float s = 0.f;
                #pragma unroll
                for (int m = 0; m < 2; ++m)
                    #pragma unroll
                    for (int j = 0; j < 4; ++j)
                        s += tanhf(acc[m][n][j] + bc);
                s += __shfl_xor(s, 16);
                s += __shfl_xor(s, 32);
                if (lhi == 0) atomicAdd(&seg[6 * N_NEUR + col], s);
            } else {
                float s = 0.f;             // rows 16..31 -> seg 5
                #pragma unroll
                for (int j = 0; j < 4; ++j)
                    s += tanhf(acc[1][n][j] + bc);
                s += __shfl_xor(s, 16);
                s += __shfl_xor(s, 32);
                if (lhi == 0) atomicAdd(&seg[5 * N_NEUR + col], s);
                #pragma unroll
                for (int j = 0; j < 4; ++j) {  // rows 0..15 per-row segments
                    int r = lhi * 4 + j;
                    int sj = (r == 0) ? 0 : (32 - __clz(r));
                    atomicAdd(&seg[sj * N_NEUR + col], tanhf(acc[0][n][j] + bc));
                }
            }
        }
    }
}

// wout[w][n] = prefix(seg)/2^w  AND  out[n] = (61/60)*sum_w cb[w][n] + 1.
__global__ __launch_bounds__(256) void winout_init(const float* __restrict__ seg,
                                                   const float* __restrict__ cb,
                                                   float* __restrict__ wout,
                                                   float* __restrict__ out) {
    int n = blockIdx.x * 256 + threadIdx.x;
    float run = 0.f;
    #pragma unroll
    for (int w = 0; w < NW; ++w) {
        run += seg[w * N_NEUR + n];
        wout[w * N_NEUR + n] = run * (1.0f / (float)(1 << w));
    }
    float bs = 0.f;
    #pragma unroll
    for (int w = 0; w < NW; ++w) bs += cb[w * N_NEUR + n];
    out[n] = 1.0166666666666666f * bs + 1.0f;
}

// out[m] += (61/60) * dot(combo_w[w][m][:], wout[w][:]) ; one wave per (w,m).
__global__ __launch_bounds__(256) void combo_dot(const float* __restrict__ cw,
                                                 const float* __restrict__ wout,
                                                 float* __restrict__ out) {
    int wid = threadIdx.x >> 6, lane = threadIdx.x & 63;
    int r = blockIdx.x * 4 + wid;             // 0..24575
    int w = r >> 11, m = r & 2047;
    const float4* row  = (const float4*)(cw + (size_t)(w * N_NEUR + m) * N_NEUR);
    const float4* wrow = (const float4*)(wout + w * N_NEUR);
    float s = 0.f;
    #pragma unroll
    for (int i = 0; i < 8; ++i) {
        float4 a = row[i * 64 + lane];
        float4 b = wrow[i * 64 + lane];
        s += a.x * b.x + a.y * b.y + a.z * b.z + a.w * b.w;
    }
    #pragma unroll
    for (int off = 32; off > 0; off >>= 1) s += __shfl_down(s, off);
    if (lane == 0) atomicAdd(&out[m], 1.0166666666666666f * s);
}

extern "C" void kernel_launch(void* const* d_in, const int* in_sizes, int n_in,
                              void* d_out, int out_size, void* d_ws, size_t ws_size,
                              hipStream_t stream) {
    const float* x  = (const float*)d_in[0];
    const float* nw = (const float*)d_in[1];
    const float* nb = (const float*)d_in[2];
    const float* cw = (const float*)d_in[3];
    const float* cb = (const float*)d_in[4];
    float* out = (float*)d_out;

    char* ws = (char*)d_ws;
    float* seg  = (float*)ws;                              // 12*2048 f32   (96 KB)
    float* wout = (float*)(ws + 98304);                    // 12*2048 f32   (96 KB)
    short* Abf  = (short*)(ws + 204800);                   // 2048*1024 bf16 (4 MB)
    short* Wbf  = (short*)(ws + 204800 + 4194304);         // 2048*1024 bf16 (4 MB)

    precast<<<4096, 256, 0, stream>>>(x + (size_t)(S_TOT - 2048) * EMB, nw, Abf, Wbf, seg);

    dim3 g1(32, 32);
    gemm_seg<<<g1, 256, 0, stream>>>(Abf, Wbf, nb, seg);

    winout_init<<<8, 256, 0, stream>>>(seg, cb, wout, out);

    combo_dot<<<6144, 256, 0, stream>>>(cw, wout, out);
}